// Round 20
// baseline (23119.870 us; speedup 1.0000x reference)
//
#include <hip/hip_runtime.h>

#define Bn 64
#define Nn 1024
#define Mn 1024
#define GSTR 16384
// scale = 2*log2(e): exp2(scale*x) = exp(2x)
#define KSCALE 2.8853900817779268f

typedef unsigned short u16;
typedef _Float16 h2 __attribute__((ext_vector_type(2)));

__device__ __forceinline__ float us2f(u16 u) {
    _Float16 h = __builtin_bit_cast(_Float16, u);
    return (float)h;
}
__device__ __forceinline__ u16 f2h(float f) {
    _Float16 h = (_Float16)f;
    return __builtin_bit_cast(u16, h);
}
__device__ __forceinline__ float rcp_fast(float x) {
#if __has_builtin(__builtin_amdgcn_rcpf)
    return __builtin_amdgcn_rcpf(x);
#else
    return 1.0f / x;
#endif
}
__device__ __forceinline__ float exp2_fast(float x) {
#if __has_builtin(__builtin_amdgcn_exp2f)
    return __builtin_amdgcn_exp2f(x);
#else
    return exp2f(x);
#endif
}
__device__ __forceinline__ float wsum(float x) {
#pragma unroll
    for (int m = 32; m > 0; m >>= 1) x += __shfl_xor(x, m, 64);
    return x;
}
__device__ __forceinline__ float wmax(float x) {
#pragma unroll
    for (int m = 32; m > 0; m >>= 1) x = fmaxf(x, __shfl_xor(x, m, 64));
    return x;
}
__device__ __forceinline__ float dot2(unsigned a, unsigned b, float c) {
#if __has_builtin(__builtin_amdgcn_fdot2)
    return __builtin_amdgcn_fdot2(__builtin_bit_cast(h2, a), __builtin_bit_cast(h2, b), c, false);
#else
    h2 av = __builtin_bit_cast(h2, a), bv = __builtin_bit_cast(h2, b);
    return c + (float)av.x * (float)bv.x + (float)av.y * (float)bv.y;
#endif
}
// AGENT-scope (device / LLC coherence point) relaxed accesses
__device__ __forceinline__ void agst(float* p, float v) {
    __hip_atomic_store(p, v, __ATOMIC_RELAXED, __HIP_MEMORY_SCOPE_AGENT);
}
__device__ __forceinline__ float agld(float* p) {
    return __hip_atomic_load(p, __ATOMIC_RELAXED, __HIP_MEMORY_SCOPE_AGENT);
}
__device__ __forceinline__ void agstu(unsigned* p, unsigned v) {
    __hip_atomic_store(p, v, __ATOMIC_RELAXED, __HIP_MEMORY_SCOPE_AGENT);
}
__device__ __forceinline__ unsigned agldu(unsigned* p) {
    return __hip_atomic_load(p, __ATOMIC_RELAXED, __HIP_MEMORY_SCOPE_AGENT);
}

// ---------- precompute: 32-row tile of  out = scale * U @ W^T  (f16 out) ----------
__global__ __launch_bounds__(256)
void gemm_f16(const float* __restrict__ U, const float* __restrict__ W,
              u16* __restrict__ outN, u16* __restrict__ outT,
              int transposed, float scale) {
    __shared__ float WL[256 * 33];
    __shared__ float uL[32 * 33];
    const int tid = threadIdx.x;
    const size_t row0 = (size_t)blockIdx.x * 32;
    float acc[32];
#pragma unroll
    for (int m = 0; m < 32; ++m) acc[m] = 0.f;
    for (int ic = 0; ic < 8; ++ic) {
        __syncthreads();
        for (int e = tid; e < 8192; e += 256) {
            int h = e >> 5, ii = e & 31;
            WL[h * 33 + ii] = W[h * 256 + ic * 32 + ii];
        }
        for (int e = tid; e < 1024; e += 256) {
            int r = e >> 5, ii = e & 31;
            uL[r * 33 + ii] = U[(row0 + r) * 256 + ic * 32 + ii];
        }
        __syncthreads();
#pragma unroll 4
        for (int ii = 0; ii < 32; ++ii) {
            float w = WL[tid * 33 + ii];
#pragma unroll
            for (int m = 0; m < 32; ++m)
                acc[m] = fmaf(w, uL[m * 33 + ii], acc[m]);
        }
    }
    if (!transposed) {
#pragma unroll
        for (int m = 0; m < 32; ++m)
            outN[(row0 + m) * 256 + tid] = f2h(scale * acc[m]);
    } else {
        __syncthreads();
#pragma unroll
        for (int m = 0; m < 32; ++m) WL[tid * 33 + m] = acc[m];
        __syncthreads();
        const size_t batch = row0 >> 10;
        const int m0 = (int)(row0 & 1023);
        for (int e = tid; e < 8192; e += 256) {
            int h = e >> 5, mm = e & 31;
            outT[(batch * 256 + h) * 1024 + m0 + mm] = f2h(scale * WL[h * 33 + mm]);
        }
    }
}

// generic pack: src f32 [R][C]  ->  dst f16 [C/8][R][8]
__global__ void pack8(const float* __restrict__ src, u16* __restrict__ dst,
                      int R, int C, float scale) {
    int idx = blockIdx.x * blockDim.x + threadIdx.x;
    int total = R * (C >> 3);
    if (idx >= total) return;
    int c8 = idx / R, r = idx - c8 * R;
    u16 pk[8];
#pragma unroll
    for (int e = 0; e < 8; ++e) pk[e] = f2h(scale * src[(size_t)r * C + c8 * 8 + e]);
    *(uint4*)&dst[(size_t)idx * 8] = *(uint4*)pk;
}

// uq f32 [64][1024 m][256 i] -> uqP f16 [64][m8=128][i=256][8]
__global__ __launch_bounds__(256)
void uq_pack(const float* __restrict__ uq, u16* __restrict__ out) {
    __shared__ float T[32][65];
    const int blk = blockIdx.x;
    const int ib = blk & 3, mt = (blk >> 2) & 31, b = blk >> 7;
    const int tid = threadIdx.x;
#pragma unroll
    for (int s = 0; s < 8; ++s) {
        int idx = tid + 256 * s, mm = idx >> 6, ii = idx & 63;
        T[mm][ii] = uq[((size_t)b * 1024 + mt * 32 + mm) * 256 + ib * 64 + ii];
    }
    __syncthreads();
    const int mo = tid >> 6, ii = tid & 63;
    u16 pk[8];
#pragma unroll
    for (int e = 0; e < 8; ++e) pk[e] = f2h(T[mo * 8 + e][ii]);
    *(uint4*)&out[(((size_t)b * 128 + mt * 4 + mo) * 256 + ib * 64 + ii) * 8] = *(uint4*)pk;
}

__global__ __launch_bounds__(1024, 4)
void scan_kernel(const float* __restrict__ up, const float* __restrict__ v0,
                 const float* __restrict__ V, const float* __restrict__ b_ih,
                 const float* __restrict__ b_hh,
                 const u16* __restrict__ WuqT, const u16* __restrict__ Pm,
                 const u16* __restrict__ uqP, const u16* __restrict__ WvP,
                 const u16* __restrict__ wihP, const u16* __restrict__ whhP,
                 const u16* __restrict__ Wg2P,
                 float* __restrict__ out, unsigned int* __restrict__ ctrs,
                 float* __restrict__ gdata) {
    const int tid = threadIdx.x;
    const int bid = blockIdx.x;
    // co-locate a batch's 4 blocks on one XCD (bid%8 = XCD under round-robin dispatch)
    const int x = bid & 7, q = (bid >> 3) & 3, bhi = bid >> 5;
    const int b = (bhi << 3) | x;

    unsigned int* flag0 = ctrs + b * 16;         // [4] step flags, barrier 0
    unsigned int* flag1 = ctrs + b * 16 + 4;     // [4] step flags, barrier 1
    float* gb = gdata + (size_t)b * GSTR;
    float* cpartF = gb;                          // [4][256] f32
    float* mlsB   = gb + 1024;                   // [8]
    unsigned* gpkB = (unsigned*)(gb + 1032);     // [4][768] packed (gi f16 | gh f16)

    __shared__ __align__(16) u16 WuqL[256 * 256];    // [h][m-slice(256)] f16, 128 KB
    __shared__ __align__(16) float scratch[2048];
    __shared__ __align__(16) float giL[768], ghL[768];   // own slice, f32 (local)
    __shared__ __align__(16) float2 dvLds[256];      // .x = d (K-scaled), .y = 2*V
    __shared__ __align__(16) float vLds[256], pnLds[256];
    __shared__ __align__(16) u16 eH[256], rH[512], vHu[256], cH[64];
    __shared__ __align__(16) float bihs[768], bhhs[768];
    __shared__ float red[32];
    __shared__ float svv_sh;

    // ---- one-time: stage this block's Wuq m-slice (256 m) into LDS ----
    {
        const unsigned* src32 = (const unsigned*)(WuqT + (size_t)b * 256 * 1024);
        unsigned* dst32 = (unsigned*)WuqL;
        for (int d = tid; d < 32768; d += 1024) {          // dwords
            int h = d >> 7, mp = d & 127;
            dst32[d] = src32[h * 512 + q * 128 + mp];
        }
    }
    if (tid < 768) { bihs[tid] = b_ih[tid]; bhhs[tid] = b_hh[tid]; }
    float vvreg = 0.f;
    if (tid < 256) {
        float v = v0[b * 256 + tid];
        vLds[tid] = v;
        vHu[tid] = f2h(v);
        vvreg = 2.0f * V[b * 256 + tid];
        pnLds[tid] = us2f(Pm[(size_t)b * Nn * 256 + tid]);
    }
    __syncthreads();
    {
        float s = wsum(vvreg);
        if ((tid & 63) == 0) red[tid >> 6] = s;
    }
    // initial d = pn + Wv@v0 (K-scaled), coalesced packed loads
    {
        const int h = tid & 255, jc = tid >> 8;            // jc 0..3
        const uint4* wv = (const uint4*)WvP;
        const unsigned* vH32 = (const unsigned*)vHu;
        float acc = 0.f;
#pragma unroll
        for (int l = 0; l < 8; ++l) {
            uint4 Wd = wv[(size_t)(jc * 8 + l) * 256 + h];
            int vb = jc * 32 + l * 4;
            acc = dot2(Wd.x, vH32[vb + 0], acc);
            acc = dot2(Wd.y, vH32[vb + 1], acc);
            acc = dot2(Wd.z, vH32[vb + 2], acc);
            acc = dot2(Wd.w, vH32[vb + 3], acc);
        }
        scratch[jc * 256 + h] = acc;
    }
    __syncthreads();
    if (tid == 0) svv_sh = 0.5f * (red[0] + red[1] + red[2] + red[3]);
    if (tid < 256)
        dvLds[tid] = make_float2(pnLds[tid] + scratch[tid] + scratch[256 + tid] +
                                 scratch[512 + tid] + scratch[768 + tid], vvreg);
    __syncthreads();
    const float SVv = svv_sh;

    const float* up_b = up + (size_t)b * Nn * 256;

    // ==== LOOP-INVARIANT uq tile in registers for the whole scan ====
    const int iD = tid & 255, mcD = tid >> 8;              // mcD 0..3 wave-uniform
    uint4 U0, U1, U2, U3, U4, U5, U6, U7;
    {
        const uint4* uqrow = (const uint4*)(uqP + (size_t)b * 128 * 256 * 8) +
                             (size_t)(q * 32 + mcD * 8) * 256 + iD;
        U0 = uqrow[0 * 256]; U1 = uqrow[1 * 256];
        U2 = uqrow[2 * 256]; U3 = uqrow[3 * 256];
        U4 = uqrow[4 * 256]; U5 = uqrow[5 * 256];
        U6 = uqrow[6 * 256]; U7 = uqrow[7 * 256];
    }

    long long budget = 1LL << 26;

    for (int t = 0; t < Nn; ++t) {
        const unsigned tgt = (unsigned)(t + 1);
        // pin U0..U7 in VGPRs (prevents rematerialization via reload)
        asm volatile("" : "+v"(U0.x), "+v"(U0.y), "+v"(U0.z), "+v"(U0.w),
                          "+v"(U1.x), "+v"(U1.y), "+v"(U1.z), "+v"(U1.w),
                          "+v"(U2.x), "+v"(U2.y), "+v"(U2.z), "+v"(U2.w),
                          "+v"(U3.x), "+v"(U3.y), "+v"(U3.z), "+v"(U3.w));
        asm volatile("" : "+v"(U4.x), "+v"(U4.y), "+v"(U4.z), "+v"(U4.w),
                          "+v"(U5.x), "+v"(U5.y), "+v"(U5.z), "+v"(U5.w),
                          "+v"(U6.x), "+v"(U6.y), "+v"(U6.z), "+v"(U6.w),
                          "+v"(U7.x), "+v"(U7.y), "+v"(U7.z), "+v"(U7.w));
        float upv = 0.f;
        if (tid < 256)
            upv = __builtin_nontemporal_load(&up_b[(size_t)t * 256 + tid]);

        // ---- B: s-partials from LDS Wuq; thread = (h-chunk, m-pair) ----
        {
            const int m2 = (tid & 127) * 2;
            const int hc = tid >> 7;                       // 0..7, wave-uniform
            float a0 = 0.f, a1 = 0.f;
            const u16* wrow = &WuqL[(hc * 32) * 256 + m2];
#pragma unroll 8
            for (int hh = 0; hh < 32; ++hh) {
                float2 dv = dvLds[hc * 32 + hh];           // wave-uniform broadcast
                unsigned w2 = *(const unsigned*)wrow;
                wrow += 256;
                float w0 = us2f((u16)(w2 & 0xffffu));
                float w1 = us2f((u16)(w2 >> 16));
                a0 = fmaf(dv.y, rcp_fast(1.f + exp2_fast(w0 + dv.x)), a0);
                a1 = fmaf(dv.y, rcp_fast(1.f + exp2_fast(w1 + dv.x)), a1);
            }
            ((float2*)scratch)[hc * 128 + (tid & 127)] = make_float2(a0, a1);
        }
        __syncthreads();

        // ---- softmax, wave-LOCAL only (64-m group per wave; no cross-wave) ----
        if (tid < 256) {
            const int m = tid;
            float sv = SVv;
#pragma unroll
            for (int c2 = 0; c2 < 8; ++c2) sv -= scratch[c2 * 256 + m];
            float mx = wmax(sv);                           // max over wave's 64 m
            float ev = __expf(sv - mx);
            eH[m] = f2h(ev);
            float sm = wsum(ev);
            if ((tid & 63) == 0) { red[tid >> 6] = mx; red[16 + (tid >> 6)] = sm; }
        }
        __syncthreads();                                   // eH + red visible

        // ---- D: cpart partial per 64-m group (scale-consistent w/ eH group) ----
        {
            const unsigned* eH32 = (const unsigned*)eH;
            float acc = 0.f;
            int eb = mcD * 32;
            acc = dot2(U0.x, eH32[eb + 0], acc);  acc = dot2(U0.y, eH32[eb + 1], acc);
            acc = dot2(U0.z, eH32[eb + 2], acc);  acc = dot2(U0.w, eH32[eb + 3], acc);
            acc = dot2(U1.x, eH32[eb + 4], acc);  acc = dot2(U1.y, eH32[eb + 5], acc);
            acc = dot2(U1.z, eH32[eb + 6], acc);  acc = dot2(U1.w, eH32[eb + 7], acc);
            acc = dot2(U2.x, eH32[eb + 8], acc);  acc = dot2(U2.y, eH32[eb + 9], acc);
            acc = dot2(U2.z, eH32[eb + 10], acc); acc = dot2(U2.w, eH32[eb + 11], acc);
            acc = dot2(U3.x, eH32[eb + 12], acc); acc = dot2(U3.y, eH32[eb + 13], acc);
            acc = dot2(U3.z, eH32[eb + 14], acc); acc = dot2(U3.w, eH32[eb + 15], acc);
            acc = dot2(U4.x, eH32[eb + 16], acc); acc = dot2(U4.y, eH32[eb + 17], acc);
            acc = dot2(U4.z, eH32[eb + 18], acc); acc = dot2(U4.w, eH32[eb + 19], acc);
            acc = dot2(U5.x, eH32[eb + 20], acc); acc = dot2(U5.y, eH32[eb + 21], acc);
            acc = dot2(U5.z, eH32[eb + 22], acc); acc = dot2(U5.w, eH32[eb + 23], acc);
            acc = dot2(U6.x, eH32[eb + 24], acc); acc = dot2(U6.y, eH32[eb + 25], acc);
            acc = dot2(U6.z, eH32[eb + 26], acc); acc = dot2(U6.w, eH32[eb + 27], acc);
            acc = dot2(U7.x, eH32[eb + 28], acc); acc = dot2(U7.y, eH32[eb + 29], acc);
            acc = dot2(U7.z, eH32[eb + 30], acc); acc = dot2(U7.w, eH32[eb + 31], acc);
            scratch[mcD * 256 + iD] = acc;
        }
        __syncthreads();

        // ---- post: fold deferred softmax combine into cpart scaling ----
        if (tid < 256) {
            float m0 = red[0], m1 = red[1], m2 = red[2], m3 = red[3];
            float mloc = fmaxf(fmaxf(m0, m1), fmaxf(m2, m3));
            float s0 = __expf(m0 - mloc), s1 = __expf(m1 - mloc);
            float s2 = __expf(m2 - mloc), s3 = __expf(m3 - mloc);
            float cp = scratch[tid] * s0 + scratch[256 + tid] * s1 +
                       scratch[512 + tid] * s2 + scratch[768 + tid] * s3;
            agst(&cpartF[q * 256 + tid], cp);
            rH[tid] = f2h(upv);                            // up half of r, pre-bar0
            if (tid == 0) {
                float sumloc = red[16] * s0 + red[17] * s1 + red[18] * s2 + red[19] * s3;
                agst(&mlsB[2 * q], mloc);
                agst(&mlsB[2 * q + 1], sumloc);
            }
        }
        __syncthreads();                                   // drains all payload stores

        // ---- bar0 ARRIVE: plain flag store (no RMW round trip) ----
        if (tid == 0) {
            asm volatile("s_waitcnt vmcnt(0)" ::: "memory");
            agstu(&flag0[q], tgt);
        }
        // ---- bar0 window: gh (all k of own slice) + E-up half ----
        float ghv = 0.f;
        if (tid < 768) {
            const uint4* wh = (const uint4*)whhP;
            const unsigned* vH32 = (const unsigned*)vHu;
#pragma unroll
            for (int l = 0; l < 8; ++l) {
                uint4 Hd = wh[(size_t)(q * 8 + l) * 768 + tid];
                int vb = q * 32 + l * 4;
                ghv = dot2(Hd.x, vH32[vb + 0], ghv);
                ghv = dot2(Hd.y, vH32[vb + 1], ghv);
                ghv = dot2(Hd.z, vH32[vb + 2], ghv);
                ghv = dot2(Hd.w, vH32[vb + 3], ghv);
            }
            ghL[tid] = ghv;                                // own slice, local f32
        }
        if (tid < 512) {                                   // E-up: ks 0..7 (k<256)
            const int o = tid & 63, ks = tid >> 6;
            const uint4* wg = (const uint4*)Wg2P;
            const unsigned* rH32 = (const unsigned*)rH;
            float acc = 0.f;
#pragma unroll
            for (int l = 0; l < 4; ++l) {
                int k8 = ks * 4 + l;
                uint4 Wd = wg[(size_t)k8 * 256 + q * 64 + o];
                int kb = k8 * 4;
                acc = dot2(Wd.x, rH32[kb + 0], acc);
                acc = dot2(Wd.y, rH32[kb + 1], acc);
                acc = dot2(Wd.z, rH32[kb + 2], acc);
                acc = dot2(Wd.w, rH32[kb + 3], acc);
            }
            scratch[ks * 64 + o] = acc;
        }
        // ---- bar0 POLL: lanes 0..3 poll the 4 flags in parallel ----
        if (tid < 4) {
            while (agldu(&flag0[tid]) < tgt) {
                __builtin_amdgcn_s_sleep(1);
                if (--budget < 0) break;                   // fail fast, no deadlock
            }
        }
        __syncthreads();

        // ---- combine softmax across 4 slices; write c half of r ----
        {
            if (tid < 256) {
                float cp0 = agld(&cpartF[tid]);       float cp1 = agld(&cpartF[256 + tid]);
                float cp2 = agld(&cpartF[512 + tid]); float cp3 = agld(&cpartF[768 + tid]);
                float m0 = agld(&mlsB[0]), s0 = agld(&mlsB[1]);
                float m1 = agld(&mlsB[2]), s1 = agld(&mlsB[3]);
                float m2 = agld(&mlsB[4]), s2 = agld(&mlsB[5]);
                float m3 = agld(&mlsB[6]), s3 = agld(&mlsB[7]);
                float Mg = fmaxf(fmaxf(m0, m1), fmaxf(m2, m3));
                float w0 = __expf(m0 - Mg), w1 = __expf(m1 - Mg);
                float w2 = __expf(m2 - Mg), w3 = __expf(m3 - Mg);
                float denom = s0 * w0 + s1 * w1 + s2 * w2 + s3 * w3;
                float c = cp0 * w0 + cp1 * w1 + cp2 * w2 + cp3 * w3;
                c *= rcp_fast(denom);
                rH[256 + tid] = f2h(c);
            }
            __syncthreads();
        }

        // ---- E-c: ks 8..15 (k>=256, uses c half) ----
        if (tid >= 512) {
            const int o = tid & 63, ks = tid >> 6;         // ks 8..15
            const uint4* wg = (const uint4*)Wg2P;
            const unsigned* rH32 = (const unsigned*)rH;
            float acc = 0.f;
#pragma unroll
            for (int l = 0; l < 4; ++l) {
                int k8 = ks * 4 + l;
                uint4 Wd = wg[(size_t)k8 * 256 + q * 64 + o];
                int kb = k8 * 4;
                acc = dot2(Wd.x, rH32[kb + 0], acc);
                acc = dot2(Wd.y, rH32[kb + 1], acc);
                acc = dot2(Wd.z, rH32[kb + 2], acc);
                acc = dot2(Wd.w, rH32[kb + 3], acc);
            }
            scratch[ks * 64 + o] = acc;
        }
        __syncthreads();
        if (tid < 64) {
            float acc = 0.f;
#pragma unroll
            for (int c2 = 0; c2 < 16; ++c2) acc += scratch[c2 * 64 + tid];
            float g = rcp_fast(1.f + __expf(-acc));
            cH[tid] = f2h(g * us2f(rH[256 + 64 * q + tid]));
        }
        __syncthreads();

        // ---- F: gi partial over own 64-k slice; post packed, keep local f32 ----
        if (tid < 768) {
            const uint4* wi = (const uint4*)wihP;
            const unsigned* cH32 = (const unsigned*)cH;
            float gi = 0.f;
#pragma unroll
            for (int l = 0; l < 8; ++l) {
                uint4 Wd = wi[(size_t)(q * 8 + l) * 768 + tid];
                int kb = l * 4;
                gi = dot2(Wd.x, cH32[kb + 0], gi);
                gi = dot2(Wd.y, cH32[kb + 1], gi);
                gi = dot2(Wd.z, cH32[kb + 2], gi);
                gi = dot2(Wd.w, cH32[kb + 3], gi);
            }
            unsigned pk = (unsigned)f2h(gi) | ((unsigned)f2h(ghv) << 16);
            agstu(&gpkB[q * 768 + tid], pk);
            giL[tid] = gi;                                 // own slice, local f32
        } else if (t + 1 < Nn) {
            const int h = tid - 768;
            pnLds[h] = us2f(Pm[((size_t)b * Nn + t + 1) * 256 + h]);
        }
        __syncthreads();                                   // drains gpk stores

        // ---- bar1 arrive (flag) + poll ----
        if (tid == 0) {
            asm volatile("s_waitcnt vmcnt(0)" ::: "memory");
            agstu(&flag1[q], tgt);
        }
        if (tid < 4) {
            while (agldu(&flag1[tid]) < tgt) {
                __builtin_amdgcn_s_sleep(1);
                if (--budget < 0) break;
            }
        }
        __syncthreads();

        // ---- gates (redundant per block, full 256 h); own slice from LDS ----
        if (tid < 256) {
            const int h = tid;
            float gir = bihs[h] + giL[h], giz = bihs[256 + h] + giL[256 + h];
            float gin = bihs[512 + h] + giL[512 + h];
            float ghr = bhhs[h] + ghL[h], ghz = bhhs[256 + h] + ghL[256 + h];
            float ghn = bhhs[512 + h] + ghL[512 + h];
#pragma unroll
            for (int s = 0; s < 4; ++s) {
                if (s == q) continue;                      // own slice already added
                unsigned* gp = &gpkB[s * 768];
                unsigned p0 = agldu(&gp[h]);
                unsigned p1 = agldu(&gp[256 + h]);
                unsigned p2 = agldu(&gp[512 + h]);
                gir += us2f((u16)(p0 & 0xffffu)); ghr += us2f((u16)(p0 >> 16));
                giz += us2f((u16)(p1 & 0xffffu)); ghz += us2f((u16)(p1 >> 16));
                gin += us2f((u16)(p2 & 0xffffu)); ghn += us2f((u16)(p2 >> 16));
            }
            float rr = rcp_fast(1.f + __expf(-(gir + ghr)));
            float zz = rcp_fast(1.f + __expf(-(giz + ghz)));
            float narg = gin + rr * ghn;
            float nn = 1.f - 2.f * rcp_fast(1.f + __expf(2.f * narg));
            float vnew = (1.f - zz) * nn + zz * vLds[h];
            if ((h >> 6) == q)
                __builtin_nontemporal_store(vnew, &out[((size_t)t * Bn + b) * 256 + h]);
            vLds[h] = vnew;
            vHu[h] = f2h(vnew);
        }
        __syncthreads();

        // ---- d for t+1 (full, local; coalesced packed Wv) ----
        if (t + 1 < Nn) {
            {
                const int h = tid & 255, jc = tid >> 8;
                const uint4* wv = (const uint4*)WvP;
                const unsigned* vH32 = (const unsigned*)vHu;
                float acc = 0.f;
#pragma unroll
                for (int l = 0; l < 8; ++l) {
                    uint4 Wd = wv[(size_t)(jc * 8 + l) * 256 + h];
                    int vb = jc * 32 + l * 4;
                    acc = dot2(Wd.x, vH32[vb + 0], acc);
                    acc = dot2(Wd.y, vH32[vb + 1], acc);
                    acc = dot2(Wd.z, vH32[vb + 2], acc);
                    acc = dot2(Wd.w, vH32[vb + 3], acc);
                }
                scratch[jc * 256 + h] = acc;
            }
            __syncthreads();
            if (tid < 256)
                dvLds[tid] = make_float2(pnLds[tid] + scratch[tid] + scratch[256 + tid] +
                                         scratch[512 + tid] + scratch[768 + tid], vvreg);
            __syncthreads();
        }
    }
}

extern "C" void kernel_launch(void* const* d_in, const int* in_sizes, int n_in,
                              void* d_out, int out_size, void* d_ws, size_t ws_size,
                              hipStream_t stream) {
    const float* up   = (const float*)d_in[0];
    const float* uq   = (const float*)d_in[1];
    const float* v0   = (const float*)d_in[2];
    const float* V    = (const float*)d_in[3];
    const float* Wp   = (const float*)d_in[4];
    const float* Wq   = (const float*)d_in[5];
    const float* Wv   = (const float*)d_in[6];
    const float* Wg   = (const float*)d_in[7];
    const float* w_ih = (const float*)d_in[8];
    const float* w_hh = (const float*)d_in[9];
    const float* b_ih = (const float*)d_in[10];
    const float* b_hh = (const float*)d_in[11];
    float* out = (float*)d_out;

    char* ws = (char*)d_ws;
    unsigned int* ctrs = (unsigned int*)ws;                  // 4 KB (flags)
    float* gdata = (float*)(ws + 8192);                      // 64*16384 f32 = 4 MB
    u16* WuqT = (u16*)(ws + (size_t)(8u << 20));             // [64][256 h][1024 m] f16, 32 MB
    u16* Pm   = WuqT + (size_t)Bn * 256 * 1024;              // [64][1024 t][256 h] f16, 32 MB
    u16* uqP  = Pm + (size_t)Bn * Nn * 256;                  // [64][128 m8][256 i][8] f16, 32 MB
    u16* WvP  = uqP + (size_t)Bn * 128 * 256 * 8;            // [32 j8][256 h][8] f16 (K-scaled)
    u16* wihP = WvP + 65536;                                 // [32 k8][768 j][8] f16
    u16* whhP = wihP + 196608;                               // [32 k8][768 j][8] f16
    u16* Wg2P = whhP + 196608;                               // [64 k8][256 o][8] f16

    hipMemsetAsync(ctrs, 0, 4096, stream);

    hipLaunchKernelGGL(gemm_f16, dim3(2048), dim3(256), 0, stream,
                       uq, Wq, (u16*)nullptr, WuqT, 1, KSCALE);
    hipLaunchKernelGGL(gemm_f16, dim3(2048), dim3(256), 0, stream,
                       up, Wp, Pm, (u16*)nullptr, 0, KSCALE);
    hipLaunchKernelGGL(uq_pack, dim3(8192), dim3(256), 0, stream, uq, uqP);
    hipLaunchKernelGGL(pack8, dim3(32), dim3(256), 0, stream, Wv, WvP, 256, 256, KSCALE);
    hipLaunchKernelGGL(pack8, dim3(96), dim3(256), 0, stream, w_ih, wihP, 768, 256, 1.0f);
    hipLaunchKernelGGL(pack8, dim3(96), dim3(256), 0, stream, w_hh, whhP, 768, 256, 1.0f);
    hipLaunchKernelGGL(pack8, dim3(64), dim3(256), 0, stream, Wg + 512 * 256, Wg2P, 256, 512, 1.0f);

    hipLaunchKernelGGL(scan_kernel, dim3(256), dim3(1024), 0, stream,
                       up, v0, V, b_ih, b_hh,
                       WuqT, Pm, uqP, WvP, wihP, whhP, Wg2P,
                       out, ctrs, gdata);
}

// Round 21
// 20279.355 us; speedup vs baseline: 1.1401x; 1.1401x over previous
//
#include <hip/hip_runtime.h>

#define Bn 64
#define Nn 1024
#define Mn 1024
#define GSTR 16384
// scale = 2*log2(e): exp2(scale*x) = exp(2x)
#define KSCALE 2.8853900817779268f

typedef unsigned short u16;
typedef _Float16 h2 __attribute__((ext_vector_type(2)));

__device__ __forceinline__ float us2f(u16 u) {
    _Float16 h = __builtin_bit_cast(_Float16, u);
    return (float)h;
}
__device__ __forceinline__ u16 f2h(float f) {
    _Float16 h = (_Float16)f;
    return __builtin_bit_cast(u16, h);
}
__device__ __forceinline__ float rcp_fast(float x) {
#if __has_builtin(__builtin_amdgcn_rcpf)
    return __builtin_amdgcn_rcpf(x);
#else
    return 1.0f / x;
#endif
}
__device__ __forceinline__ float exp2_fast(float x) {
#if __has_builtin(__builtin_amdgcn_exp2f)
    return __builtin_amdgcn_exp2f(x);
#else
    return exp2f(x);
#endif
}
__device__ __forceinline__ float wsum(float x) {
#pragma unroll
    for (int m = 32; m > 0; m >>= 1) x += __shfl_xor(x, m, 64);
    return x;
}
__device__ __forceinline__ float wmax(float x) {
#pragma unroll
    for (int m = 32; m > 0; m >>= 1) x = fmaxf(x, __shfl_xor(x, m, 64));
    return x;
}
__device__ __forceinline__ float dot2(unsigned a, unsigned b, float c) {
#if __has_builtin(__builtin_amdgcn_fdot2)
    return __builtin_amdgcn_fdot2(__builtin_bit_cast(h2, a), __builtin_bit_cast(h2, b), c, false);
#else
    h2 av = __builtin_bit_cast(h2, a), bv = __builtin_bit_cast(h2, b);
    return c + (float)av.x * (float)bv.x + (float)av.y * (float)bv.y;
#endif
}
// AGENT-scope (device / LLC coherence point) relaxed accesses
__device__ __forceinline__ void agst(float* p, float v) {
    __hip_atomic_store(p, v, __ATOMIC_RELAXED, __HIP_MEMORY_SCOPE_AGENT);
}
__device__ __forceinline__ float agld(float* p) {
    return __hip_atomic_load(p, __ATOMIC_RELAXED, __HIP_MEMORY_SCOPE_AGENT);
}
__device__ __forceinline__ void agstu(unsigned* p, unsigned v) {
    __hip_atomic_store(p, v, __ATOMIC_RELAXED, __HIP_MEMORY_SCOPE_AGENT);
}
__device__ __forceinline__ unsigned agldu(unsigned* p) {
    return __hip_atomic_load(p, __ATOMIC_RELAXED, __HIP_MEMORY_SCOPE_AGENT);
}

// ---------- precompute: 32-row tile of  out = scale * U @ W^T  (f16 out) ----------
__global__ __launch_bounds__(256)
void gemm_f16(const float* __restrict__ U, const float* __restrict__ W,
              u16* __restrict__ outN, u16* __restrict__ outT,
              int transposed, float scale) {
    __shared__ float WL[256 * 33];
    __shared__ float uL[32 * 33];
    const int tid = threadIdx.x;
    const size_t row0 = (size_t)blockIdx.x * 32;
    float acc[32];
#pragma unroll
    for (int m = 0; m < 32; ++m) acc[m] = 0.f;
    for (int ic = 0; ic < 8; ++ic) {
        __syncthreads();
        for (int e = tid; e < 8192; e += 256) {
            int h = e >> 5, ii = e & 31;
            WL[h * 33 + ii] = W[h * 256 + ic * 32 + ii];
        }
        for (int e = tid; e < 1024; e += 256) {
            int r = e >> 5, ii = e & 31;
            uL[r * 33 + ii] = U[(row0 + r) * 256 + ic * 32 + ii];
        }
        __syncthreads();
#pragma unroll 4
        for (int ii = 0; ii < 32; ++ii) {
            float w = WL[tid * 33 + ii];
#pragma unroll
            for (int m = 0; m < 32; ++m)
                acc[m] = fmaf(w, uL[m * 33 + ii], acc[m]);
        }
    }
    if (!transposed) {
#pragma unroll
        for (int m = 0; m < 32; ++m)
            outN[(row0 + m) * 256 + tid] = f2h(scale * acc[m]);
    } else {
        __syncthreads();
#pragma unroll
        for (int m = 0; m < 32; ++m) WL[tid * 33 + m] = acc[m];
        __syncthreads();
        const size_t batch = row0 >> 10;
        const int m0 = (int)(row0 & 1023);
        for (int e = tid; e < 8192; e += 256) {
            int h = e >> 5, mm = e & 31;
            outT[(batch * 256 + h) * 1024 + m0 + mm] = f2h(scale * WL[h * 33 + mm]);
        }
    }
}

// generic pack: src f32 [R][C]  ->  dst f16 [C/8][R][8]
__global__ void pack8(const float* __restrict__ src, u16* __restrict__ dst,
                      int R, int C, float scale) {
    int idx = blockIdx.x * blockDim.x + threadIdx.x;
    int total = R * (C >> 3);
    if (idx >= total) return;
    int c8 = idx / R, r = idx - c8 * R;
    u16 pk[8];
#pragma unroll
    for (int e = 0; e < 8; ++e) pk[e] = f2h(scale * src[(size_t)r * C + c8 * 8 + e]);
    *(uint4*)&dst[(size_t)idx * 8] = *(uint4*)pk;
}

// uq f32 [64][1024 m][256 i] -> uqP f16 [64][m8=128][i=256][8]
__global__ __launch_bounds__(256)
void uq_pack(const float* __restrict__ uq, u16* __restrict__ out) {
    __shared__ float T[32][65];
    const int blk = blockIdx.x;
    const int ib = blk & 3, mt = (blk >> 2) & 31, b = blk >> 7;
    const int tid = threadIdx.x;
#pragma unroll
    for (int s = 0; s < 8; ++s) {
        int idx = tid + 256 * s, mm = idx >> 6, ii = idx & 63;
        T[mm][ii] = uq[((size_t)b * 1024 + mt * 32 + mm) * 256 + ib * 64 + ii];
    }
    __syncthreads();
    const int mo = tid >> 6, ii = tid & 63;
    u16 pk[8];
#pragma unroll
    for (int e = 0; e < 8; ++e) pk[e] = f2h(T[mo * 8 + e][ii]);
    *(uint4*)&out[(((size_t)b * 128 + mt * 4 + mo) * 256 + ib * 64 + ii) * 8] = *(uint4*)pk;
}

__global__ __launch_bounds__(1024, 4)
void scan_kernel(const float* __restrict__ up, const float* __restrict__ v0,
                 const float* __restrict__ V, const float* __restrict__ b_ih,
                 const float* __restrict__ b_hh,
                 const u16* __restrict__ WuqT, const u16* __restrict__ Pm,
                 const u16* __restrict__ uqP, const u16* __restrict__ WvP,
                 const u16* __restrict__ wihP, const u16* __restrict__ whhP,
                 const u16* __restrict__ Wg2P,
                 float* __restrict__ out, unsigned int* __restrict__ ctrs,
                 float* __restrict__ gdata) {
    const int tid = threadIdx.x;
    const int bid = blockIdx.x;
    // co-locate a batch's 4 blocks on one XCD (bid%8 = XCD under round-robin dispatch)
    const int x = bid & 7, q = (bid >> 3) & 3, bhi = bid >> 5;
    const int b = (bhi << 3) | x;

    unsigned int* flag0 = ctrs + b * 16;         // [4] step flags, barrier 0
    unsigned int* flag1 = ctrs + b * 16 + 4;     // [4] step flags, barrier 1
    float* gb = gdata + (size_t)b * GSTR;
    float* cpartF = gb;                          // [4][256] f32
    float* mlsB   = gb + 1024;                   // [8]
    unsigned* gpkB = (unsigned*)(gb + 1032);     // [4][768] packed (gi f16 | gh f16)

    __shared__ __align__(16) u16 WuqL[256 * 256];    // [h][m-slice(256)] f16, 128 KB
    __shared__ __align__(16) float scratch[2048];
    __shared__ __align__(16) float giL[768], ghL[768];   // own slice, f32 (local)
    __shared__ __align__(16) float2 dvLds[256];      // .x = d (K-scaled), .y = 2*V
    __shared__ __align__(16) float vLds[256], pnLds[256];
    __shared__ __align__(16) u16 eH[256], rH[512], vHu[256], cH[64];
    __shared__ __align__(16) float bihs[768], bhhs[768];
    __shared__ float red[32];
    __shared__ float svv_sh;

    // ---- one-time: stage this block's Wuq m-slice (256 m) into LDS ----
    {
        const unsigned* src32 = (const unsigned*)(WuqT + (size_t)b * 256 * 1024);
        unsigned* dst32 = (unsigned*)WuqL;
        for (int d = tid; d < 32768; d += 1024) {          // dwords
            int h = d >> 7, mp = d & 127;
            dst32[d] = src32[h * 512 + q * 128 + mp];
        }
    }
    if (tid < 768) { bihs[tid] = b_ih[tid]; bhhs[tid] = b_hh[tid]; }
    float vvreg = 0.f;
    if (tid < 256) {
        float v = v0[b * 256 + tid];
        vLds[tid] = v;
        vHu[tid] = f2h(v);
        vvreg = 2.0f * V[b * 256 + tid];
        pnLds[tid] = us2f(Pm[(size_t)b * Nn * 256 + tid]);
    }
    __syncthreads();
    {
        float s = wsum(vvreg);
        if ((tid & 63) == 0) red[tid >> 6] = s;
    }
    // initial d = pn + Wv@v0 (K-scaled), coalesced packed loads
    {
        const int h = tid & 255, jc = tid >> 8;            // jc 0..3
        const uint4* wv = (const uint4*)WvP;
        const unsigned* vH32 = (const unsigned*)vHu;
        float acc = 0.f;
#pragma unroll
        for (int l = 0; l < 8; ++l) {
            uint4 Wd = wv[(size_t)(jc * 8 + l) * 256 + h];
            int vb = jc * 32 + l * 4;
            acc = dot2(Wd.x, vH32[vb + 0], acc);
            acc = dot2(Wd.y, vH32[vb + 1], acc);
            acc = dot2(Wd.z, vH32[vb + 2], acc);
            acc = dot2(Wd.w, vH32[vb + 3], acc);
        }
        scratch[jc * 256 + h] = acc;
    }
    __syncthreads();
    if (tid == 0) svv_sh = 0.5f * (red[0] + red[1] + red[2] + red[3]);
    if (tid < 256)
        dvLds[tid] = make_float2(pnLds[tid] + scratch[tid] + scratch[256 + tid] +
                                 scratch[512 + tid] + scratch[768 + tid], vvreg);
    __syncthreads();
    const float SVv = svv_sh;

    const float* up_b = up + (size_t)b * Nn * 256;

    // ==== LOOP-INVARIANT uq tile in registers for the whole scan ====
    const int iD = tid & 255, mcD = tid >> 8;              // mcD 0..3 wave-uniform
    uint4 U0, U1, U2, U3, U4, U5, U6, U7;
    {
        const uint4* uqrow = (const uint4*)(uqP + (size_t)b * 128 * 256 * 8) +
                             (size_t)(q * 32 + mcD * 8) * 256 + iD;
        U0 = uqrow[0 * 256]; U1 = uqrow[1 * 256];
        U2 = uqrow[2 * 256]; U3 = uqrow[3 * 256];
        U4 = uqrow[4 * 256]; U5 = uqrow[5 * 256];
        U6 = uqrow[6 * 256]; U7 = uqrow[7 * 256];
    }

    long long budget = 1LL << 26;
    float mloc, sumloc;

    for (int t = 0; t < Nn; ++t) {
        const unsigned tgt = (unsigned)(t + 1);
        // pin U0..U7 in VGPRs: empty asm "redefines" them, so the compiler
        // cannot rematerialize by reloading from memory each iteration.
        asm volatile("" : "+v"(U0.x), "+v"(U0.y), "+v"(U0.z), "+v"(U0.w),
                          "+v"(U1.x), "+v"(U1.y), "+v"(U1.z), "+v"(U1.w),
                          "+v"(U2.x), "+v"(U2.y), "+v"(U2.z), "+v"(U2.w),
                          "+v"(U3.x), "+v"(U3.y), "+v"(U3.z), "+v"(U3.w));
        asm volatile("" : "+v"(U4.x), "+v"(U4.y), "+v"(U4.z), "+v"(U4.w),
                          "+v"(U5.x), "+v"(U5.y), "+v"(U5.z), "+v"(U5.w),
                          "+v"(U6.x), "+v"(U6.y), "+v"(U6.z), "+v"(U6.w),
                          "+v"(U7.x), "+v"(U7.y), "+v"(U7.z), "+v"(U7.w));
        float upv = 0.f;
        if (tid < 256)
            upv = __builtin_nontemporal_load(&up_b[(size_t)t * 256 + tid]);

        // ---- B: s-partials from LDS Wuq; thread = (h-chunk, m-pair) ----
        {
            const int m2 = (tid & 127) * 2;
            const int hc = tid >> 7;                       // 0..7, wave-uniform
            float a0 = 0.f, a1 = 0.f;
            const u16* wrow = &WuqL[(hc * 32) * 256 + m2];
#pragma unroll 8
            for (int hh = 0; hh < 32; ++hh) {
                float2 dv = dvLds[hc * 32 + hh];           // wave-uniform broadcast
                unsigned w2 = *(const unsigned*)wrow;
                wrow += 256;
                float w0 = us2f((u16)(w2 & 0xffffu));
                float w1 = us2f((u16)(w2 >> 16));
                a0 = fmaf(dv.y, rcp_fast(1.f + exp2_fast(w0 + dv.x)), a0);
                a1 = fmaf(dv.y, rcp_fast(1.f + exp2_fast(w1 + dv.x)), a1);
            }
            ((float2*)scratch)[hc * 128 + (tid & 127)] = make_float2(a0, a1);
        }
        __syncthreads();

        // ---- local softmax over this block's 256 m ----
        {
            const int m = tid & 255;
            float sv = SVv;
#pragma unroll
            for (int c2 = 0; c2 < 8; ++c2) sv -= scratch[c2 * 256 + m];
            if (tid >= 256) sv = -3.0e38f;
            float mx = wmax(sv);
            if ((tid & 63) == 0) red[tid >> 6] = mx;
            __syncthreads();
            mloc = red[0];
#pragma unroll
            for (int w2 = 1; w2 < 16; ++w2) mloc = fmaxf(mloc, red[w2]);
            float ev = __expf(sv - mloc);
            if (tid < 256) eH[m] = f2h(ev);
            float sm = wsum(ev);
            if ((tid & 63) == 0) red[16 + (tid >> 6)] = sm;
            __syncthreads();
            sumloc = red[16] + red[17] + red[18] + red[19];
        }

        // ---- D: cpart[i] = sum_m e[m]*uq[m][i]; pure-register MACs ----
        {
            const unsigned* eH32 = (const unsigned*)eH;
            float acc = 0.f;
            int eb = mcD * 32;
            acc = dot2(U0.x, eH32[eb + 0], acc);  acc = dot2(U0.y, eH32[eb + 1], acc);
            acc = dot2(U0.z, eH32[eb + 2], acc);  acc = dot2(U0.w, eH32[eb + 3], acc);
            acc = dot2(U1.x, eH32[eb + 4], acc);  acc = dot2(U1.y, eH32[eb + 5], acc);
            acc = dot2(U1.z, eH32[eb + 6], acc);  acc = dot2(U1.w, eH32[eb + 7], acc);
            acc = dot2(U2.x, eH32[eb + 8], acc);  acc = dot2(U2.y, eH32[eb + 9], acc);
            acc = dot2(U2.z, eH32[eb + 10], acc); acc = dot2(U2.w, eH32[eb + 11], acc);
            acc = dot2(U3.x, eH32[eb + 12], acc); acc = dot2(U3.y, eH32[eb + 13], acc);
            acc = dot2(U3.z, eH32[eb + 14], acc); acc = dot2(U3.w, eH32[eb + 15], acc);
            acc = dot2(U4.x, eH32[eb + 16], acc); acc = dot2(U4.y, eH32[eb + 17], acc);
            acc = dot2(U4.z, eH32[eb + 18], acc); acc = dot2(U4.w, eH32[eb + 19], acc);
            acc = dot2(U5.x, eH32[eb + 20], acc); acc = dot2(U5.y, eH32[eb + 21], acc);
            acc = dot2(U5.z, eH32[eb + 22], acc); acc = dot2(U5.w, eH32[eb + 23], acc);
            acc = dot2(U6.x, eH32[eb + 24], acc); acc = dot2(U6.y, eH32[eb + 25], acc);
            acc = dot2(U6.z, eH32[eb + 26], acc); acc = dot2(U6.w, eH32[eb + 27], acc);
            acc = dot2(U7.x, eH32[eb + 28], acc); acc = dot2(U7.y, eH32[eb + 29], acc);
            acc = dot2(U7.z, eH32[eb + 30], acc); acc = dot2(U7.w, eH32[eb + 31], acc);
            scratch[mcD * 256 + iD] = acc;
        }
        __syncthreads();
        if (tid < 256)
            agst(&cpartF[q * 256 + tid], scratch[tid] + scratch[256 + tid] +
                                         scratch[512 + tid] + scratch[768 + tid]);
        if (tid == 0) { agst(&mlsB[2 * q], mloc); agst(&mlsB[2 * q + 1], sumloc); }
        __syncthreads();                                   // drains all payload stores

        // ---- bar0 ARRIVE: plain flag store (no RMW round trip) ----
        if (tid == 0) {
            asm volatile("s_waitcnt vmcnt(0)" ::: "memory");
            agstu(&flag0[q], tgt);
        }
        // ---- gh = w_hh @ v_{t-1}, own 64-k slice — overlaps bar0 wait ----
        float ghv = 0.f;
        if (tid < 768) {
            const uint4* wh = (const uint4*)whhP;
            const unsigned* vH32 = (const unsigned*)vHu;
#pragma unroll
            for (int l = 0; l < 8; ++l) {
                uint4 Hd = wh[(size_t)(q * 8 + l) * 768 + tid];
                int vb = q * 32 + l * 4;
                ghv = dot2(Hd.x, vH32[vb + 0], ghv);
                ghv = dot2(Hd.y, vH32[vb + 1], ghv);
                ghv = dot2(Hd.z, vH32[vb + 2], ghv);
                ghv = dot2(Hd.w, vH32[vb + 3], ghv);
            }
            ghL[tid] = ghv;                                // own slice, local f32
        }
        // ---- bar0 POLL: lanes 0..3 poll the 4 flags in parallel ----
        if (tid < 4) {
            while (agldu(&flag0[tid]) < tgt) {
                __builtin_amdgcn_s_sleep(1);
                if (--budget < 0) break;                   // fail fast, no deadlock
            }
        }
        __syncthreads();

        // ---- combine softmax across 4 slices; r = [up_t, c] (1 sync only) ----
        {
            if (tid < 256) {
                float cp0 = agld(&cpartF[tid]);       float cp1 = agld(&cpartF[256 + tid]);
                float cp2 = agld(&cpartF[512 + tid]); float cp3 = agld(&cpartF[768 + tid]);
                float m0 = agld(&mlsB[0]), s0 = agld(&mlsB[1]);
                float m1 = agld(&mlsB[2]), s1 = agld(&mlsB[3]);
                float m2 = agld(&mlsB[4]), s2 = agld(&mlsB[5]);
                float m3 = agld(&mlsB[6]), s3 = agld(&mlsB[7]);
                float Mg = fmaxf(fmaxf(m0, m1), fmaxf(m2, m3));
                float w0 = __expf(m0 - Mg), w1 = __expf(m1 - Mg);
                float w2 = __expf(m2 - Mg), w3 = __expf(m3 - Mg);
                float denom = s0 * w0 + s1 * w1 + s2 * w2 + s3 * w3;
                float c = cp0 * w0 + cp1 * w1 + cp2 * w2 + cp3 * w3;
                c *= rcp_fast(denom);
                rH[tid] = f2h(upv);
                rH[256 + tid] = f2h(c);
            }
            __syncthreads();
        }

        // ---- E: g = sigmoid(Wg2 @ r) for own 64 o (== own k-slice) ----
        {
            const int o = tid & 63, ks = tid >> 6;         // ks 0..15
            const uint4* wg = (const uint4*)Wg2P;
            const unsigned* rH32 = (const unsigned*)rH;
            float acc = 0.f;
#pragma unroll
            for (int l = 0; l < 4; ++l) {
                int k8 = ks * 4 + l;
                uint4 Wd = wg[(size_t)k8 * 256 + q * 64 + o];
                int kb = k8 * 4;
                acc = dot2(Wd.x, rH32[kb + 0], acc);
                acc = dot2(Wd.y, rH32[kb + 1], acc);
                acc = dot2(Wd.z, rH32[kb + 2], acc);
                acc = dot2(Wd.w, rH32[kb + 3], acc);
            }
            scratch[ks * 64 + o] = acc;
        }
        __syncthreads();
        if (tid < 64) {
            float acc = 0.f;
#pragma unroll
            for (int c2 = 0; c2 < 16; ++c2) acc += scratch[c2 * 64 + tid];
            float g = rcp_fast(1.f + __expf(-acc));
            cH[tid] = f2h(g * us2f(rH[256 + 64 * q + tid]));
        }
        __syncthreads();

        // ---- F: gi partial over own 64-k slice; post packed, keep local f32 ----
        if (tid < 768) {
            const uint4* wi = (const uint4*)wihP;
            const unsigned* cH32 = (const unsigned*)cH;
            float gi = 0.f;
#pragma unroll
            for (int l = 0; l < 8; ++l) {
                uint4 Wd = wi[(size_t)(q * 8 + l) * 768 + tid];
                int kb = l * 4;
                gi = dot2(Wd.x, cH32[kb + 0], gi);
                gi = dot2(Wd.y, cH32[kb + 1], gi);
                gi = dot2(Wd.z, cH32[kb + 2], gi);
                gi = dot2(Wd.w, cH32[kb + 3], gi);
            }
            unsigned pk = (unsigned)f2h(gi) | ((unsigned)f2h(ghv) << 16);
            agstu(&gpkB[q * 768 + tid], pk);
            giL[tid] = gi;                                 // own slice, local f32
        } else if (t + 1 < Nn) {
            const int h = tid - 768;
            pnLds[h] = us2f(Pm[((size_t)b * Nn + t + 1) * 256 + h]);
        }
        __syncthreads();                                   // drains gpk stores

        // ---- bar1 arrive (flag) + poll ----
        if (tid == 0) {
            asm volatile("s_waitcnt vmcnt(0)" ::: "memory");
            agstu(&flag1[q], tgt);
        }
        if (tid < 4) {
            while (agldu(&flag1[tid]) < tgt) {
                __builtin_amdgcn_s_sleep(1);
                if (--budget < 0) break;
            }
        }
        __syncthreads();

        // ---- gates (redundant per block, full 256 h); own slice from LDS ----
        if (tid < 256) {
            const int h = tid;
            float gir = bihs[h] + giL[h], giz = bihs[256 + h] + giL[256 + h];
            float gin = bihs[512 + h] + giL[512 + h];
            float ghr = bhhs[h] + ghL[h], ghz = bhhs[256 + h] + ghL[256 + h];
            float ghn = bhhs[512 + h] + ghL[512 + h];
#pragma unroll
            for (int s = 0; s < 4; ++s) {
                if (s == q) continue;                      // own slice already added
                unsigned* gp = &gpkB[s * 768];
                unsigned p0 = agldu(&gp[h]);
                unsigned p1 = agldu(&gp[256 + h]);
                unsigned p2 = agldu(&gp[512 + h]);
                gir += us2f((u16)(p0 & 0xffffu)); ghr += us2f((u16)(p0 >> 16));
                giz += us2f((u16)(p1 & 0xffffu)); ghz += us2f((u16)(p1 >> 16));
                gin += us2f((u16)(p2 & 0xffffu)); ghn += us2f((u16)(p2 >> 16));
            }
            float rr = rcp_fast(1.f + __expf(-(gir + ghr)));
            float zz = rcp_fast(1.f + __expf(-(giz + ghz)));
            float narg = gin + rr * ghn;
            float nn = 1.f - 2.f * rcp_fast(1.f + __expf(2.f * narg));
            float vnew = (1.f - zz) * nn + zz * vLds[h];
            if ((h >> 6) == q)
                __builtin_nontemporal_store(vnew, &out[((size_t)t * Bn + b) * 256 + h]);
            vLds[h] = vnew;
            vHu[h] = f2h(vnew);
        }
        __syncthreads();

        // ---- d for t+1 (full, local; coalesced packed Wv) ----
        if (t + 1 < Nn) {
            {
                const int h = tid & 255, jc = tid >> 8;
                const uint4* wv = (const uint4*)WvP;
                const unsigned* vH32 = (const unsigned*)vHu;
                float acc = 0.f;
#pragma unroll
                for (int l = 0; l < 8; ++l) {
                    uint4 Wd = wv[(size_t)(jc * 8 + l) * 256 + h];
                    int vb = jc * 32 + l * 4;
                    acc = dot2(Wd.x, vH32[vb + 0], acc);
                    acc = dot2(Wd.y, vH32[vb + 1], acc);
                    acc = dot2(Wd.z, vH32[vb + 2], acc);
                    acc = dot2(Wd.w, vH32[vb + 3], acc);
                }
                scratch[jc * 256 + h] = acc;
            }
            __syncthreads();
            if (tid < 256)
                dvLds[tid] = make_float2(pnLds[tid] + scratch[tid] + scratch[256 + tid] +
                                         scratch[512 + tid] + scratch[768 + tid], vvreg);
            __syncthreads();
        }
    }
}

extern "C" void kernel_launch(void* const* d_in, const int* in_sizes, int n_in,
                              void* d_out, int out_size, void* d_ws, size_t ws_size,
                              hipStream_t stream) {
    const float* up   = (const float*)d_in[0];
    const float* uq   = (const float*)d_in[1];
    const float* v0   = (const float*)d_in[2];
    const float* V    = (const float*)d_in[3];
    const float* Wp   = (const float*)d_in[4];
    const float* Wq   = (const float*)d_in[5];
    const float* Wv   = (const float*)d_in[6];
    const float* Wg   = (const float*)d_in[7];
    const float* w_ih = (const float*)d_in[8];
    const float* w_hh = (const float*)d_in[9];
    const float* b_ih = (const float*)d_in[10];
    const float* b_hh = (const float*)d_in[11];
    float* out = (float*)d_out;

    char* ws = (char*)d_ws;
    unsigned int* ctrs = (unsigned int*)ws;                  // 4 KB (flags)
    float* gdata = (float*)(ws + 8192);                      // 64*16384 f32 = 4 MB
    u16* WuqT = (u16*)(ws + (size_t)(8u << 20));             // [64][256 h][1024 m] f16, 32 MB
    u16* Pm   = WuqT + (size_t)Bn * 256 * 1024;              // [64][1024 t][256 h] f16, 32 MB
    u16* uqP  = Pm + (size_t)Bn * Nn * 256;                  // [64][128 m8][256 i][8] f16, 32 MB
    u16* WvP  = uqP + (size_t)Bn * 128 * 256 * 8;            // [32 j8][256 h][8] f16 (K-scaled)
    u16* wihP = WvP + 65536;                                 // [32 k8][768 j][8] f16
    u16* whhP = wihP + 196608;                               // [32 k8][768 j][8] f16
    u16* Wg2P = whhP + 196608;                               // [64 k8][256 o][8] f16

    hipMemsetAsync(ctrs, 0, 4096, stream);

    hipLaunchKernelGGL(gemm_f16, dim3(2048), dim3(256), 0, stream,
                       uq, Wq, (u16*)nullptr, WuqT, 1, KSCALE);
    hipLaunchKernelGGL(gemm_f16, dim3(2048), dim3(256), 0, stream,
                       up, Wp, Pm, (u16*)nullptr, 0, KSCALE);
    hipLaunchKernelGGL(uq_pack, dim3(8192), dim3(256), 0, stream, uq, uqP);
    hipLaunchKernelGGL(pack8, dim3(32), dim3(256), 0, stream, Wv, WvP, 256, 256, KSCALE);
    hipLaunchKernelGGL(pack8, dim3(96), dim3(256), 0, stream, w_ih, wihP, 768, 256, 1.0f);
    hipLaunchKernelGGL(pack8, dim3(96), dim3(256), 0, stream, w_hh, whhP, 768, 256, 1.0f);
    hipLaunchKernelGGL(pack8, dim3(64), dim3(256), 0, stream, Wg + 512 * 256, Wg2P, 256, 512, 1.0f);

    hipLaunchKernelGGL(scan_kernel, dim3(256), dim3(1024), 0, stream,
                       up, v0, V, b_ih, b_hh,
                       WuqT, Pm, uqP, WvP, wihP, whhP, Wg2P,
                       out, ctrs, gdata);
}